// Round 9
// baseline (60.717 us; speedup 1.0000x reference)
//
#include <hip/hip_runtime.h>
#include <hip/hip_bf16.h>
#include <math.h>

constexpr int D      = 2048;
constexpr int NE     = 64;
constexpr int TOKENS = 16384;   // 4*4096
constexpr int TPB    = 64;      // tokens per block -> 256 blocks, 1/CU, no tail
constexpr int NBLK   = TOKENS / TPB;
constexpr int NWAVE  = 8;       // k-slices
constexpr int KSLICE = D / NWAVE;   // 256
constexpr int KC     = 32;      // k per MFMA step
constexpr int NKC    = KSLICE / KC; // 8
constexpr int PAD    = 66;

typedef __attribute__((ext_vector_type(8))) short bf16x8;
typedef __attribute__((ext_vector_type(4))) float f32x4;

static __device__ inline unsigned short f2bf_u(float x) {
  __hip_bfloat16 h = __float2bfloat16(x);   // RNE
  unsigned short u; __builtin_memcpy(&u, &h, 2); return u;
}
static __device__ inline float bfu2f(unsigned short u) {
  __hip_bfloat16 h; __builtin_memcpy(&h, &u, 2);
  return __bfloat162float(h);
}

// split 8 f32 into hi/lo bf16 — bit-identical to rounds 2-8
static __device__ inline void cvt_hilo(const float* f, bf16x8& hi, bf16x8& lo) {
#pragma unroll
  for (int j = 0; j < 8; ++j) {
    unsigned short h = f2bf_u(f[j]);
    float hf = bfu2f(h);
    unsigned short lw = f2bf_u(f[j] - hf);
    hi[j] = (short)h;
    lo[j] = (short)lw;
  }
}

// pre-kernel: W (64x2048 f32) -> Whi/Wlo bf16 (bit-identical split)
__global__ __launch_bounds__(256)
void prep_w(const float* __restrict__ W, unsigned short* __restrict__ Whi,
            unsigned short* __restrict__ Wlo) {
  const int i = (blockIdx.x * 256 + threadIdx.x) * 4;
  float4 v = *reinterpret_cast<const float4*>(W + i);
  float f[4] = {v.x, v.y, v.z, v.w};
#pragma unroll
  for (int j = 0; j < 4; ++j) {
    unsigned short h = f2bf_u(f[j]);
    float hf = bfu2f(h);
    Whi[i + j] = h;
    Wlo[i + j] = f2bf_u(f[j] - hf);
  }
}

__global__ __launch_bounds__(1024, 4)   // 16 waves/block, cap 128 VGPR -> 16 waves/CU
void router_main(const float* __restrict__ X,
                 const unsigned short* __restrict__ Whi,
                 const unsigned short* __restrict__ Wlo,
                 const float* __restrict__ bias,
                 float* __restrict__ out) {
  __shared__ float red[4][TPB][PAD];   // 67.6 KB, used twice (k-slices 0-3 then 4-7)
  __shared__ int   i1s[TPB], i2s[TPB];
  __shared__ float p1s[TPB], p2s[TPB];

  const int t  = threadIdx.x;
  const int wv = t >> 6;        // wave 0..15
  const int w  = wv & 7;        // k-slice id (same k-split as rounds 2-8)
  const int h  = wv >> 3;       // m-half: tokens [h*32, h*32+32)
  const int l  = t & 63;
  const int lm = l & 15;        // M-row / N-col in 16x16 tile
  const int lk = l >> 4;        // k-group -> k offset lk*8
  // XCD swizzle: xcd = bid%8 gets contiguous token range (L2/DRAM locality)
  const int tile = (blockIdx.x & 7) * (NBLK / 8) + (blockIdx.x >> 3);
  const int tok0 = tile * TPB;

  f32x4 acc[2][4];
#pragma unroll
  for (int m = 0; m < 2; ++m)
#pragma unroll
    for (int n = 0; n < 4; ++n) acc[m][n] = (f32x4){0.f, 0.f, 0.f, 0.f};

  const unsigned short* whp = Whi + (size_t)lm * D + w * KSLICE + lk * 8;
  const unsigned short* wlp = Wlo + (size_t)lm * D + w * KSLICE + lk * 8;
  const float* xr[2];
#pragma unroll
  for (int m = 0; m < 2; ++m)   // global m-tile index = h*2 + m
    xr[m] = X + (size_t)(tok0 + (h * 2 + m) * 16 + lm) * D + w * KSLICE + lk * 8;

  // X staging, double-buffered one kc ahead
  float4 c0[2], c1[2];
#pragma unroll
  for (int m = 0; m < 2; ++m) {
    c0[m] = *reinterpret_cast<const float4*>(xr[m]);
    c1[m] = *reinterpret_cast<const float4*>(xr[m] + 4);
  }

#pragma unroll
  for (int kc = 0; kc < NKC; ++kc) {
    const int ko = kc * KC;

    // batched B loads: 8 independent dwordx4 in flight (L1-shared across the m-half pair)
    bf16x8 bh[4], bl[4];
#pragma unroll
    for (int n = 0; n < 4; ++n) {
      bh[n] = *reinterpret_cast<const bf16x8*>(whp + (size_t)n * 16 * D + ko);
      bl[n] = *reinterpret_cast<const bf16x8*>(wlp + (size_t)n * 16 * D + ko);
    }

    // prefetch next-kc X for both m-tiles
    float4 n0[2], n1[2];
    if (kc < NKC - 1) {
#pragma unroll
      for (int m = 0; m < 2; ++m) {
        n0[m] = *reinterpret_cast<const float4*>(xr[m] + (kc + 1) * KC);
        n1[m] = *reinterpret_cast<const float4*>(xr[m] + (kc + 1) * KC + 4);
      }
    }

#pragma unroll
    for (int m = 0; m < 2; ++m) {            // same kc / hh,hl,lh,ll order as rounds 2-8
      float f[8];
      *reinterpret_cast<float4*>(&f[0]) = c0[m];
      *reinterpret_cast<float4*>(&f[4]) = c1[m];
      bf16x8 ah, al;
      cvt_hilo(f, ah, al);
#pragma unroll
      for (int n = 0; n < 4; ++n) {
        acc[m][n] = __builtin_amdgcn_mfma_f32_16x16x32_bf16(ah, bh[n], acc[m][n], 0, 0, 0);
        acc[m][n] = __builtin_amdgcn_mfma_f32_16x16x32_bf16(ah, bl[n], acc[m][n], 0, 0, 0);
        acc[m][n] = __builtin_amdgcn_mfma_f32_16x16x32_bf16(al, bh[n], acc[m][n], 0, 0, 0);
        acc[m][n] = __builtin_amdgcn_mfma_f32_16x16x32_bf16(al, bl[n], acc[m][n], 0, 0, 0);
      }
    }
    if (kc < NKC - 1) {
#pragma unroll
      for (int m = 0; m < 2; ++m) { c0[m] = n0[m]; c1[m] = n1[m]; }
    }
  }

  // ---- two-batch cross-wave reduce; bias + w0+...+w7 order exact (as rounds 2-8) ----
  const int rtok = t >> 4;          // 0..63
  const int re0  = (t & 15) * 4;    // 0..60
  float s[4];

  if (w < 4) {                       // batch 1: k-slices 0..3 stash (both m-halves)
#pragma unroll
    for (int m = 0; m < 2; ++m)
#pragma unroll
      for (int n = 0; n < 4; ++n)
#pragma unroll
        for (int j = 0; j < 4; ++j)
          red[w][(h * 2 + m) * 16 + lk * 4 + j][n * 16 + lm] = acc[m][n][j];
  }
  __syncthreads();
#pragma unroll
  for (int q = 0; q < 4; ++q) {
    const int e = re0 + q;
    float v = bias[e];
#pragma unroll
    for (int ww = 0; ww < 4; ++ww) v += red[ww][rtok][e];
    s[q] = v;
  }
  __syncthreads();
  if (w >= 4) {                      // batch 2: k-slices 4..7 stash (same buffer)
#pragma unroll
    for (int m = 0; m < 2; ++m)
#pragma unroll
      for (int n = 0; n < 4; ++n)
#pragma unroll
        for (int j = 0; j < 4; ++j)
          red[w - 4][(h * 2 + m) * 16 + lk * 4 + j][n * 16 + lm] = acc[m][n][j];
  }
  __syncthreads();
#pragma unroll
  for (int q = 0; q < 4; ++q) {
    const int e = re0 + q;
    float v = s[q];
#pragma unroll
    for (int ww = 0; ww < 4; ++ww) v += red[ww][rtok][e];
    red[0][rtok][e] = v;             // 1:1 slot ownership
  }
  __syncthreads();

  // ---- top-2 + softmax weights (threads 0..63, one token each) ----
  if (t < TPB) {
    float m1 = -INFINITY, m2 = -INFINITY;
    int j1 = 0, j2 = 0;
    for (int e = 0; e < NE; ++e) {
      const float v = red[0][t][e];
      if (v > m1) { m2 = m1; j2 = j1; m1 = v; j1 = e; }     // strict >: lax.top_k tie-break
      else if (v > m2) { m2 = v; j2 = e; }
    }
    const float e2  = expf(m2 - m1);
    const float inv = 1.0f / (1.0f + e2);
    i1s[t] = j1; i2s[t] = j2;
    p1s[t] = inv; p2s[t] = e2 * inv;
    float* oidx = out + (size_t)TOKENS * NE + (size_t)(tok0 + t) * 2;
    oidx[0] = (float)j1;
    oidx[1] = (float)j2;
  }
  __syncthreads();

  // ---- coalesced sf write: 1024 thr -> (token = t>>4, experts 4*(t&15)..+3) ----
  {
    const int tok = t >> 4;
    const int e0  = (t & 15) * 4;
    const int j1 = i1s[tok], j2 = i2s[tok];
    const float pa = p1s[tok], pb2 = p2s[tok];
    float vv[4];
#pragma unroll
    for (int q = 0; q < 4; ++q) {
      const int e = e0 + q;
      vv[q] = (e == j1) ? pa : ((e == j2) ? pb2 : 0.f);
    }
    *reinterpret_cast<float4*>(out + (size_t)(tok0 + tok) * NE + e0) =
        make_float4(vv[0], vv[1], vv[2], vv[3]);
  }
}

extern "C" void kernel_launch(void* const* d_in, const int* in_sizes, int n_in,
                              void* d_out, int out_size, void* d_ws, size_t ws_size,
                              hipStream_t stream) {
  const float* X = (const float*)d_in[0];
  const float* W = (const float*)d_in[1];
  const float* B = (const float*)d_in[2];
  float* out = (float*)d_out;

  unsigned short* Whi = (unsigned short*)d_ws;     // 256 KB
  unsigned short* Wlo = Whi + (size_t)NE * D;      // 256 KB

  prep_w<<<dim3(NE * D / (256 * 4)), dim3(256), 0, stream>>>(W, Whi, Wlo);
  router_main<<<dim3(NBLK), dim3(1024), 0, stream>>>(X, Whi, Wlo, B, out);
}